// Round 15
// baseline (54.602 us; speedup 1.0000x reference)
//
#include <hip/hip_runtime.h>
#include <hip/hip_bf16.h>

constexpr int NBATCH = 2048;   // B*T
constexpr int N      = 128;    // nodes
constexpr float INVTAU = 20.0f;   // 1/0.05
constexpr float EPSF   = 1e-8f;
constexpr float MUF    = 1.0f / 128.0f;   // mu = nu = 1/N

typedef __attribute__((ext_vector_type(8))) short short8;   // 8 x bf16 MFMA frag
typedef __attribute__((ext_vector_type(4))) float f32x4;    // MFMA accumulator
typedef __attribute__((ext_vector_type(2))) float f32x2;    // packed pair -> v_pk_fma_f32

static __device__ __forceinline__ float fastrcp(float x) {
    return __builtin_amdgcn_rcpf(x);    // v_rcp_f32, ~1e-7 rel err
}
static __device__ __forceinline__ float fastsqrt(float x) {
    return __builtin_amdgcn_sqrtf(x);   // raw v_sqrt_f32
}
// C recovered from K in phase 4 (frees 16 ccp regs -> room for the KT strip):
// C = -tau*ln(K). K==0 (the universal case here: exp(~-226) underflows) ->
// log2=-inf -> clamp; K*C_clamped = 0 exactly (r14 validated, absmax 0.0).
static __device__ __forceinline__ float cfromk(float k) {
    return fminf(-0.03465735903f * __log2f(k), 1e30f);
}

// DPP add: VALU-pipe cross-lane, NO DS op (r10: DS pipe was the bottleneck).
template <int CTRL>
static __device__ __forceinline__ float dpp_add(float s) {
    union { float f; int i; } a, b;
    a.f = s;
    b.i = __builtin_amdgcn_update_dpp(0, a.i, CTRL, 0xF, 0xF, false);
    return s + b.f;
}
// all-reduce over a 16-lane row: row_ror 8,4,2,1
static __device__ __forceinline__ float row16_allreduce(float s) {
    s = dpp_add<0x128>(s);   // row_ror:8
    s = dpp_add<0x124>(s);   // row_ror:4
    s = dpp_add<0x122>(s);   // row_ror:2
    s = dpp_add<0x121>(s);   // row_ror:1
    return s;
}
// all-reduce over an 8-lane group: quad_perm xor1, xor2, then half_mirror
static __device__ __forceinline__ float grp8_allreduce(float s) {
    s = dpp_add<0x0B1>(s);   // quad_perm [1,0,3,2]  (xor 1)
    s = dpp_add<0x04E>(s);   // quad_perm [2,3,0,1]  (xor 2)
    s = dpp_add<0x141>(s);   // row_half_mirror      (xor 7 within 8)
    return s;
}

// ROUND 15: dual-strip scheme. Wave w holds BOTH K rows 16w..16w+15 (kk2)
// and K^T rows 16w..16w+15 (kkT2, via 8 extra MFMAs with src/tgt swapped).
// Sinkhorn iteration is then two IN-WAVE DPP reductions; the only LDS
// traffic is redistributing u and v (2x b128 read + 4 scalar writes per
// lx==0 lane), killing the sPartF partial machinery (r10 lever: DS ops).
// Lane (lx=l&15, lh=l>>4): kk2 rows 16w+4lh+q cols 16tc+lx;
//                          kkT2 rows (=K cols) 16w+4lh+q cols (=K rows) 16tc+lx.
// u,v transposed in LDS: s[idx&15][idx>>4] at stride 12.
// bounds(512,4): the mapped no-spill point (r5/r7/r12/r14 all spilled above
// it). Tripwire: WRITE_SIZE ~64 KB, VGPR <= ~110.
__global__ __launch_bounds__(512, 4)
void sinkhorn_batch(const float* __restrict__ srcg,
                    const float* __restrict__ tgtg,
                    float* __restrict__ lossg)
{
    __shared__ ushort sStage[2 * N * 64];   // 32 KB staging
    __shared__ float sX2[N], sY2[N];
    __shared__ float sUt[16 * 12], sVt[16 * 12];   // transposed u, v
    __shared__ float sRed[8];

    ushort* sA = sStage;
    ushort* sB = sStage + N * 64;

    const int t  = threadIdx.x;
    const int l  = t & 63;
    const int w  = t >> 6;       // wave 0..7
    const int lx = l & 15;
    const int lh = l >> 4;       // 0..3
    const int bt = blockIdx.x;

    const float4* sg4 = reinterpret_cast<const float4*>(srcg + (size_t)bt * (N * 64));
    const float4* tg4 = reinterpret_cast<const float4*>(tgtg + (size_t)bt * (N * 64));

    // ---- phase 0: stage bf16 (swizzled, b128 stores) + norms via 8-lane DPP ----
    #pragma unroll
    for (int it = 0; it < 2; ++it) {
        int tp = t + 512 * it;         // 0..1023; 8 consecutive lanes = one row
        int r  = tp >> 3;
        int d8 = tp & 7;
        int f0 = tp * 2;
        float4 a0 = sg4[f0], a1 = sg4[f0 + 1];
        float4 b0 = tg4[f0], b1 = tg4[f0 + 1];
        float pa = a0.x * a0.x + a0.y * a0.y + a0.z * a0.z + a0.w * a0.w
                 + a1.x * a1.x + a1.y * a1.y + a1.z * a1.z + a1.w * a1.w;
        float pb = b0.x * b0.x + b0.y * b0.y + b0.z * b0.z + b0.w * b0.w
                 + b1.x * b1.x + b1.y * b1.y + b1.z * b1.z + b1.w * b1.w;
        pa = grp8_allreduce(pa);
        pb = grp8_allreduce(pb);
        if (d8 == 0) { sX2[r] = pa; sY2[r] = pb; }

        int idx = r * 64 + ((d8 ^ (r & 7)) << 3);   // b128 slot (16B aligned)
        union { __hip_bfloat162 h[4]; uint4 u; } ca, cb;
        ca.h[0] = __float22bfloat162_rn(make_float2(a0.x, a0.y));
        ca.h[1] = __float22bfloat162_rn(make_float2(a0.z, a0.w));
        ca.h[2] = __float22bfloat162_rn(make_float2(a1.x, a1.y));
        ca.h[3] = __float22bfloat162_rn(make_float2(a1.z, a1.w));
        cb.h[0] = __float22bfloat162_rn(make_float2(b0.x, b0.y));
        cb.h[1] = __float22bfloat162_rn(make_float2(b0.z, b0.w));
        cb.h[2] = __float22bfloat162_rn(make_float2(b1.x, b1.y));
        cb.h[3] = __float22bfloat162_rn(make_float2(b1.z, b1.w));
        *reinterpret_cast<uint4*>(&sA[idx]) = ca.u;
        *reinterpret_cast<uint4*>(&sB[idx]) = cb.u;
    }
    __syncthreads();

    // ---- phase 1+2: K strip then KT strip (src/tgt roles swapped) ----
    f32x2 kk2[8][2];     // K[16w+4lh+q][16tc+lx]
    f32x2 kkT2[8][2];    // K[16tc+lx][16w+4lh+q]  (= KT strip)
    {
        float y2c[8];
        #pragma unroll
        for (int tc = 0; tc < 8; ++tc) y2c[tc] = sY2[16 * tc + lx];
        f32x4 x2q = *reinterpret_cast<const f32x4*>(&sX2[16 * w + 4 * lh]);
        int ra = 16 * w + lx;
        short8 af0 = *reinterpret_cast<const short8*>(&sA[ra * 64 + (((0 + lh) ^ (ra & 7)) << 3)]);
        short8 af1 = *reinterpret_cast<const short8*>(&sA[ra * 64 + (((4 + lh) ^ (ra & 7)) << 3)]);
        #pragma unroll
        for (int tc = 0; tc < 8; ++tc) {
            int rb = 16 * tc + lx;
            short8 bf0 = *reinterpret_cast<const short8*>(&sB[rb * 64 + (((0 + lh) ^ (rb & 7)) << 3)]);
            short8 bf1 = *reinterpret_cast<const short8*>(&sB[rb * 64 + (((4 + lh) ^ (rb & 7)) << 3)]);
            f32x4 acc = (f32x4){0.f, 0.f, 0.f, 0.f};
            acc = __builtin_amdgcn_mfma_f32_16x16x32_bf16(af0, bf0, acc, 0, 0, 0);
            acc = __builtin_amdgcn_mfma_f32_16x16x32_bf16(af1, bf1, acc, 0, 0, 0);
            float cd[4];
            #pragma unroll
            for (int q = 0; q < 4; ++q)
                cd[q] = fastsqrt(fmaxf(x2q[q] + y2c[tc] - 2.0f * acc[q], 0.f));
            kk2[tc][0] = (f32x2){__expf(-INVTAU * cd[0]), __expf(-INVTAU * cd[1])};
            kk2[tc][1] = (f32x2){__expf(-INVTAU * cd[2]), __expf(-INVTAU * cd[3])};
        }
    }
    {
        float x2c[8];
        #pragma unroll
        for (int tc = 0; tc < 8; ++tc) x2c[tc] = sX2[16 * tc + lx];
        f32x4 y2q = *reinterpret_cast<const f32x4*>(&sY2[16 * w + 4 * lh]);
        int ra = 16 * w + lx;
        short8 af0 = *reinterpret_cast<const short8*>(&sB[ra * 64 + (((0 + lh) ^ (ra & 7)) << 3)]);
        short8 af1 = *reinterpret_cast<const short8*>(&sB[ra * 64 + (((4 + lh) ^ (ra & 7)) << 3)]);
        #pragma unroll
        for (int tc = 0; tc < 8; ++tc) {
            int rb = 16 * tc + lx;
            short8 bf0 = *reinterpret_cast<const short8*>(&sA[rb * 64 + (((0 + lh) ^ (rb & 7)) << 3)]);
            short8 bf1 = *reinterpret_cast<const short8*>(&sA[rb * 64 + (((4 + lh) ^ (rb & 7)) << 3)]);
            f32x4 acc = (f32x4){0.f, 0.f, 0.f, 0.f};
            acc = __builtin_amdgcn_mfma_f32_16x16x32_bf16(af0, bf0, acc, 0, 0, 0);
            acc = __builtin_amdgcn_mfma_f32_16x16x32_bf16(af1, bf1, acc, 0, 0, 0);
            float cd[4];
            #pragma unroll
            for (int q = 0; q < 4; ++q)
                cd[q] = fastsqrt(fmaxf(y2q[q] + x2c[tc] - 2.0f * acc[q], 0.f));
            kkT2[tc][0] = (f32x2){__expf(-INVTAU * cd[0]), __expf(-INVTAU * cd[1])};
            kkT2[tc][1] = (f32x2){__expf(-INVTAU * cd[2]), __expf(-INVTAU * cd[3])};
        }
    }
    // no barrier: staging is not reused; sUt/sVt are separate buffers

    // ---- phase 3: Sinkhorn, both matvecs in-wave; LDS only redistributes u,v --
    f32x2 uu2[2];
    for (int iter = 0; iter < 5; ++iter) {
        // u_i = mu / (sum_j K[i][j] v[j] + eps)
        f32x4 v03, v47;
        if (iter == 0) {
            v03 = (f32x4){1.f, 1.f, 1.f, 1.f};
            v47 = (f32x4){1.f, 1.f, 1.f, 1.f};
        } else {
            const f32x4* pv = reinterpret_cast<const f32x4*>(&sVt[lx * 12]);
            v03 = pv[0];
            v47 = pv[1];
        }
        f32x2 p0 = (f32x2){0.f, 0.f}, p1 = (f32x2){0.f, 0.f};
        #pragma unroll
        for (int tc = 0; tc < 8; ++tc) {
            float vs = (tc < 4) ? v03[tc & 3] : v47[tc & 3];
            f32x2 vb = (f32x2){vs, vs};
            p0 = kk2[tc][0] * vb + p0;      // v_pk_fma_f32
            p1 = kk2[tc][1] * vb + p1;
        }
        uu2[0] = (f32x2){MUF * fastrcp(row16_allreduce(p0.x) + EPSF),
                         MUF * fastrcp(row16_allreduce(p0.y) + EPSF)};
        uu2[1] = (f32x2){MUF * fastrcp(row16_allreduce(p1.x) + EPSF),
                         MUF * fastrcp(row16_allreduce(p1.y) + EPSF)};
        if (lx == 0) {   // u[16w+4lh+q] -> sUt[(4lh+q)*12 + w]
            sUt[(4 * lh + 0) * 12 + w] = uu2[0].x;
            sUt[(4 * lh + 1) * 12 + w] = uu2[0].y;
            sUt[(4 * lh + 2) * 12 + w] = uu2[1].x;
            sUt[(4 * lh + 3) * 12 + w] = uu2[1].y;
        }
        __syncthreads();

        // v_j = nu / (sum_i K[i][j] u[i] + eps)  via KT strip, in-wave
        f32x4 u03, u47;
        {
            const f32x4* pu = reinterpret_cast<const f32x4*>(&sUt[lx * 12]);
            u03 = pu[0];
            u47 = pu[1];
        }
        f32x2 q0 = (f32x2){0.f, 0.f}, q1 = (f32x2){0.f, 0.f};
        #pragma unroll
        for (int tc = 0; tc < 8; ++tc) {
            float us = (tc < 4) ? u03[tc & 3] : u47[tc & 3];
            f32x2 ub = (f32x2){us, us};
            q0 = kkT2[tc][0] * ub + q0;
            q1 = kkT2[tc][1] * ub + q1;
        }
        float w0 = MUF * fastrcp(row16_allreduce(q0.x) + EPSF);
        float w1 = MUF * fastrcp(row16_allreduce(q0.y) + EPSF);
        float w2 = MUF * fastrcp(row16_allreduce(q1.x) + EPSF);
        float w3 = MUF * fastrcp(row16_allreduce(q1.y) + EPSF);
        if (lx == 0) {   // v[16w+4lh+q] -> sVt[(4lh+q)*12 + w]
            sVt[(4 * lh + 0) * 12 + w] = w0;
            sVt[(4 * lh + 1) * 12 + w] = w1;
            sVt[(4 * lh + 2) * 12 + w] = w2;
            sVt[(4 * lh + 3) * 12 + w] = w3;
        }
        __syncthreads();
    }

    // ---- phase 4: loss = sum u_i K_ij C_ij v_j; C recovered via cfromk ----
    f32x4 v03, v47;
    {
        const f32x4* pv = reinterpret_cast<const f32x4*>(&sVt[lx * 12]);
        v03 = pv[0];
        v47 = pv[1];
    }

    float part = 0.f;
    #pragma unroll
    for (int tc = 0; tc < 8; ++tc) {
        f32x2 k0 = kk2[tc][0], k1 = kk2[tc][1];
        f32x2 c0 = (f32x2){cfromk(k0.x), cfromk(k0.y)};
        f32x2 c1 = (f32x2){cfromk(k1.x), cfromk(k1.y)};
        f32x2 r2 = uu2[0] * k0 * c0 + uu2[1] * k1 * c1;
        float vs = (tc < 4) ? v03[tc & 3] : v47[tc & 3];
        part += (r2.x + r2.y) * vs;
    }

    // deterministic block reduce: DPP within 16, then 2 cross-row shuffles
    part = row16_allreduce(part);
    part += __shfl_xor(part, 16);
    part += __shfl_xor(part, 32);
    if (l == 0) sRed[w] = part;
    __syncthreads();
    if (t == 0) {
        float s = 0.f;
        #pragma unroll
        for (int i = 0; i < 8; ++i) s += sRed[i];
        lossg[bt] = s;
    }
}

// mean over 2048 per-frame losses -> d_out[0]
__global__ __launch_bounds__(256, 1)
void reduce_mean(const float* __restrict__ lossg, float* __restrict__ out)
{
    __shared__ float sRed[4];
    int t = threadIdx.x;
    float s = 0.f;
    #pragma unroll
    for (int it = 0; it < 8; ++it) s += lossg[t + 256 * it];
    #pragma unroll
    for (int off = 32; off >= 1; off >>= 1) s += __shfl_xor(s, off);
    if ((t & 63) == 0) sRed[t >> 6] = s;
    __syncthreads();
    if (t == 0) out[0] = (sRed[0] + sRed[1] + sRed[2] + sRed[3]) * (1.0f / 2048.0f);
}

extern "C" void kernel_launch(void* const* d_in, const int* in_sizes, int n_in,
                              void* d_out, int out_size, void* d_ws, size_t ws_size,
                              hipStream_t stream)
{
    const float* src = (const float*)d_in[0];
    const float* tgt = (const float*)d_in[1];
    float* ws = (float*)d_ws;                       // 2048 floats of scratch

    sinkhorn_batch<<<NBATCH, 512, 0, stream>>>(src, tgt, ws);
    reduce_mean<<<1, 256, 0, stream>>>(ws, (float*)d_out);
}

// Round 16
// 49.341 us; speedup vs baseline: 1.1066x; 1.1066x over previous
//
#include <hip/hip_runtime.h>
#include <hip/hip_bf16.h>

constexpr int NBATCH = 2048;   // B*T
constexpr int N      = 128;    // nodes
constexpr float INVTAU = 20.0f;   // 1/0.05
constexpr float EPSF   = 1e-8f;
constexpr float MUF    = 1.0f / 128.0f;   // mu = nu = 1/N

typedef __attribute__((ext_vector_type(8))) short short8;   // 8 x bf16 MFMA frag
typedef __attribute__((ext_vector_type(4))) float f32x4;    // MFMA accumulator
typedef __attribute__((ext_vector_type(2))) float f32x2;    // packed pair -> v_pk_fma_f32

static __device__ __forceinline__ float fastrcp(float x) {
    return __builtin_amdgcn_rcpf(x);    // v_rcp_f32, ~1e-7 rel err
}
static __device__ __forceinline__ float fastsqrt(float x) {
    return __builtin_amdgcn_sqrtf(x);   // raw v_sqrt_f32
}
// C recovered from K in phase 4 (frees the 16 ccp regs -> 2 batches of fp32 K
// fit in 64 persistent regs): C = -tau*ln(K). K==0 (universal here:
// exp(~-226) underflows) -> log2=-inf -> clamp; K*C_clamped = 0 exactly
// (r14 validated, absmax 0.0). K>0: log-of-exp roundtrip ~1e-7 rel.
static __device__ __forceinline__ float cfromk(float k) {
    return fminf(-0.03465735903f * __log2f(k), 1e30f);
}

// DPP add: VALU-pipe cross-lane, NO DS op (r10: DS pipe was the bottleneck).
template <int CTRL>
static __device__ __forceinline__ float dpp_add(float s) {
    union { float f; int i; } a, b;
    a.f = s;
    b.i = __builtin_amdgcn_update_dpp(0, a.i, CTRL, 0xF, 0xF, false);
    return s + b.f;
}
// all-reduce over a 16-lane row: row_ror 8,4,2,1
static __device__ __forceinline__ float row16_allreduce(float s) {
    s = dpp_add<0x128>(s);   // row_ror:8
    s = dpp_add<0x124>(s);   // row_ror:4
    s = dpp_add<0x122>(s);   // row_ror:2
    s = dpp_add<0x121>(s);   // row_ror:1
    return s;
}
// all-reduce over an 8-lane group: quad_perm xor1, xor2, then half_mirror
static __device__ __forceinline__ float grp8_allreduce(float s) {
    s = dpp_add<0x0B1>(s);   // quad_perm [1,0,3,2]  (xor 1)
    s = dpp_add<0x04E>(s);   // quad_perm [2,3,0,1]  (xor 2)
    s = dpp_add<0x141>(s);   // row_half_mirror      (xor 7 within 8)
    return s;
}

// ROUND 16: TWO batches per block, fp32 K only (64 persistent regs; r7's
// spill was 96: kk+ccp). Amortizes the 10 phase-3 barriers over 2 batches
// and doubles phase-3 ILP (two independent dot->DPP->rcp chains per wave)
// at unchanged occupancy (2 blocks/CU, LDS 67.6 KB).
// 512 threads = 8 waves; wave w owns rows 16w..16w+15 of BOTH batches.
// Lane (lx=l&15, lh=l>>4) owns rows 16w+4lh+q (q<4), cols 16tc+lx (tc<8).
// v transposed per batch: sVt[g][lx*12+tc]. C via cfromk (no ccp regs).
// bounds(512,4): the mapped no-spill point. Tripwire: WRITE ~64 KB, VGPR<=128.
__global__ __launch_bounds__(512, 4)
void sinkhorn_batch(const float* __restrict__ srcg,
                    const float* __restrict__ tgtg,
                    float* __restrict__ lossg)
{
    // staging 64 KB (2 batches); dead after phase 1 -> overlaid by sPartF
    // [2*128 cols][36 f32] = 36 KB
    __shared__ ushort sStage[4 * N * 64];
    __shared__ float sX2[2][N], sY2[2][N];
    __shared__ float sVt[2][16 * 12];      // transposed v per batch
    __shared__ float sRed[2][8];

    float* sPartF = reinterpret_cast<float*>(sStage);

    const int t  = threadIdx.x;
    const int l  = t & 63;
    const int w  = t >> 6;       // wave 0..7
    const int lx = l & 15;
    const int lh = l >> 4;       // 0..3
    const int bt0 = blockIdx.x * 2;

    // ---- phase 0: stage both batches bf16 (swizzled, b128) + norms via DPP ----
    #pragma unroll
    for (int it = 0; it < 4; ++it) {
        const int g  = it >> 1;
        const int tp = t + 512 * (it & 1);   // 0..1023; 8 lanes = one row
        const float4* sg4 = reinterpret_cast<const float4*>(srcg + (size_t)(bt0 + g) * (N * 64));
        const float4* tg4 = reinterpret_cast<const float4*>(tgtg + (size_t)(bt0 + g) * (N * 64));
        int r  = tp >> 3;
        int d8 = tp & 7;
        int f0 = tp * 2;
        float4 a0 = sg4[f0], a1 = sg4[f0 + 1];
        float4 b0 = tg4[f0], b1 = tg4[f0 + 1];
        float pa = a0.x * a0.x + a0.y * a0.y + a0.z * a0.z + a0.w * a0.w
                 + a1.x * a1.x + a1.y * a1.y + a1.z * a1.z + a1.w * a1.w;
        float pb = b0.x * b0.x + b0.y * b0.y + b0.z * b0.z + b0.w * b0.w
                 + b1.x * b1.x + b1.y * b1.y + b1.z * b1.z + b1.w * b1.w;
        pa = grp8_allreduce(pa);
        pb = grp8_allreduce(pb);
        if (d8 == 0) { sX2[g][r] = pa; sY2[g][r] = pb; }

        int idx = g * (2 * N * 64) + r * 64 + ((d8 ^ (r & 7)) << 3);
        union { __hip_bfloat162 h[4]; uint4 u; } ca, cb;
        ca.h[0] = __float22bfloat162_rn(make_float2(a0.x, a0.y));
        ca.h[1] = __float22bfloat162_rn(make_float2(a0.z, a0.w));
        ca.h[2] = __float22bfloat162_rn(make_float2(a1.x, a1.y));
        ca.h[3] = __float22bfloat162_rn(make_float2(a1.z, a1.w));
        cb.h[0] = __float22bfloat162_rn(make_float2(b0.x, b0.y));
        cb.h[1] = __float22bfloat162_rn(make_float2(b0.z, b0.w));
        cb.h[2] = __float22bfloat162_rn(make_float2(b1.x, b1.y));
        cb.h[3] = __float22bfloat162_rn(make_float2(b1.z, b1.w));
        *reinterpret_cast<uint4*>(&sStage[idx]) = ca.u;
        *reinterpret_cast<uint4*>(&sStage[idx + N * 64]) = cb.u;
    }
    __syncthreads();

    // ---- phase 1+2: per batch, per col-tile MFMA -> K (fp32, 32 regs each) ----
    f32x2 kk2[2][8][2];      // kk2[g][tc][p] = {K[q=2p], K[q=2p+1]}
    #pragma unroll
    for (int g = 0; g < 2; ++g) {
        const ushort* sA = &sStage[g * (2 * N * 64)];
        const ushort* sB = sA + N * 64;
        float y2c[8];
        #pragma unroll
        for (int tc = 0; tc < 8; ++tc) y2c[tc] = sY2[g][16 * tc + lx];
        f32x4 x2q = *reinterpret_cast<const f32x4*>(&sX2[g][16 * w + 4 * lh]);
        int ra = 16 * w + lx;
        short8 af0 = *reinterpret_cast<const short8*>(&sA[ra * 64 + (((0 + lh) ^ (ra & 7)) << 3)]);
        short8 af1 = *reinterpret_cast<const short8*>(&sA[ra * 64 + (((4 + lh) ^ (ra & 7)) << 3)]);
        #pragma unroll
        for (int tc = 0; tc < 8; ++tc) {
            int rb = 16 * tc + lx;
            short8 bf0 = *reinterpret_cast<const short8*>(&sB[rb * 64 + (((0 + lh) ^ (rb & 7)) << 3)]);
            short8 bf1 = *reinterpret_cast<const short8*>(&sB[rb * 64 + (((4 + lh) ^ (rb & 7)) << 3)]);
            f32x4 acc = (f32x4){0.f, 0.f, 0.f, 0.f};
            acc = __builtin_amdgcn_mfma_f32_16x16x32_bf16(af0, bf0, acc, 0, 0, 0);
            acc = __builtin_amdgcn_mfma_f32_16x16x32_bf16(af1, bf1, acc, 0, 0, 0);
            float cd[4];
            #pragma unroll
            for (int q = 0; q < 4; ++q)
                cd[q] = fastsqrt(fmaxf(x2q[q] + y2c[tc] - 2.0f * acc[q], 0.f));
            kk2[g][tc][0] = (f32x2){__expf(-INVTAU * cd[0]), __expf(-INVTAU * cd[1])};
            kk2[g][tc][1] = (f32x2){__expf(-INVTAU * cd[2]), __expf(-INVTAU * cd[3])};
        }
    }

    __syncthreads();   // staging reads done -> region becomes sPartF
                       // (no sVt init: iter 0 uses v==1 from registers)

    // ---- phase 3: Sinkhorn, both batches per iteration (shared barriers) ----
    f32x2 uu2[2][2];   // uu2[g][p]
    for (int iter = 0; iter < 5; ++iter) {
        // u = mu / (K v + eps): packed dots + DPP row-reduce, per batch
        #pragma unroll
        for (int g = 0; g < 2; ++g) {
            f32x4 v03, v47;
            if (iter == 0) {
                v03 = (f32x4){1.f, 1.f, 1.f, 1.f};
                v47 = (f32x4){1.f, 1.f, 1.f, 1.f};
            } else {
                const f32x4* pv = reinterpret_cast<const f32x4*>(&sVt[g][lx * 12]);
                v03 = pv[0];
                v47 = pv[1];
            }
            f32x2 p0 = (f32x2){0.f, 0.f}, p1 = (f32x2){0.f, 0.f};
            #pragma unroll
            for (int tc = 0; tc < 8; ++tc) {
                float vs = (tc < 4) ? v03[tc & 3] : v47[tc & 3];
                f32x2 vb = (f32x2){vs, vs};
                p0 = kk2[g][tc][0] * vb + p0;      // v_pk_fma_f32
                p1 = kk2[g][tc][1] * vb + p1;
            }
            uu2[g][0] = (f32x2){MUF * fastrcp(row16_allreduce(p0.x) + EPSF),
                                MUF * fastrcp(row16_allreduce(p0.y) + EPSF)};
            uu2[g][1] = (f32x2){MUF * fastrcp(row16_allreduce(p1.x) + EPSF),
                                MUF * fastrcp(row16_allreduce(p1.y) + EPSF)};
        }
        // no barrier: u never touches LDS

        // v = nu / (K^T u + eps): per-lane 4-row partials -> sPartF, both batches
        #pragma unroll
        for (int g = 0; g < 2; ++g)
            #pragma unroll
            for (int tc = 0; tc < 8; ++tc) {
                f32x2 t2 = kk2[g][tc][0] * uu2[g][0] + kk2[g][tc][1] * uu2[g][1];
                sPartF[(g * N + tc * 16 + lx) * 36 + (w << 2) + lh] = t2.x + t2.y;
            }
        __syncthreads();
        {
            // 512 threads cover 256 (g,col) pairs x 2 halves:
            // c = t>>1: g = c>>7, col = c&127; ht = t&1 reads 16 partials.
            int c = t >> 1, ht = t & 1;
            const f32x4* pr = reinterpret_cast<const f32x4*>(&sPartF[c * 36 + ht * 16]);
            f32x4 a0 = pr[0], a1 = pr[1], a2 = pr[2], a3 = pr[3];
            f32x4 ss = (a0 + a1) + (a2 + a3);
            float s = (ss[0] + ss[1]) + (ss[2] + ss[3]);
            s = dpp_add<0x0B1>(s);     // quad_perm xor1: combine the two halves
            if (ht == 0) {
                int g = c >> 7, col = c & 127;
                sVt[g][(col & 15) * 12 + (col >> 4)] = MUF * fastrcp(s + EPSF);
            }
        }
        __syncthreads();
    }

    // ---- phase 4: loss = sum u K C v per batch; C recovered via cfromk ----
    #pragma unroll
    for (int g = 0; g < 2; ++g) {
        f32x4 v03, v47;
        {
            const f32x4* pv = reinterpret_cast<const f32x4*>(&sVt[g][lx * 12]);
            v03 = pv[0];
            v47 = pv[1];
        }
        float part = 0.f;
        #pragma unroll
        for (int tc = 0; tc < 8; ++tc) {
            f32x2 k0 = kk2[g][tc][0], k1 = kk2[g][tc][1];
            f32x2 c0 = (f32x2){cfromk(k0.x), cfromk(k0.y)};
            f32x2 c1 = (f32x2){cfromk(k1.x), cfromk(k1.y)};
            f32x2 r2 = uu2[g][0] * k0 * c0 + uu2[g][1] * k1 * c1;
            float vs = (tc < 4) ? v03[tc & 3] : v47[tc & 3];
            part += (r2.x + r2.y) * vs;
        }
        part = row16_allreduce(part);
        part += __shfl_xor(part, 16);
        part += __shfl_xor(part, 32);
        if (l == 0) sRed[g][w] = part;
    }
    __syncthreads();
    if (t < 2) {
        float s = 0.f;
        #pragma unroll
        for (int i = 0; i < 8; ++i) s += sRed[t][i];
        lossg[bt0 + t] = s;
    }
}

// mean over 2048 per-frame losses -> d_out[0]
__global__ __launch_bounds__(256, 1)
void reduce_mean(const float* __restrict__ lossg, float* __restrict__ out)
{
    __shared__ float sRed[4];
    int t = threadIdx.x;
    float s = 0.f;
    #pragma unroll
    for (int it = 0; it < 8; ++it) s += lossg[t + 256 * it];
    #pragma unroll
    for (int off = 32; off >= 1; off >>= 1) s += __shfl_xor(s, off);
    if ((t & 63) == 0) sRed[t >> 6] = s;
    __syncthreads();
    if (t == 0) out[0] = (sRed[0] + sRed[1] + sRed[2] + sRed[3]) * (1.0f / 2048.0f);
}

extern "C" void kernel_launch(void* const* d_in, const int* in_sizes, int n_in,
                              void* d_out, int out_size, void* d_ws, size_t ws_size,
                              hipStream_t stream)
{
    const float* src = (const float*)d_in[0];
    const float* tgt = (const float*)d_in[1];
    float* ws = (float*)d_ws;                       // 2048 floats of scratch

    sinkhorn_batch<<<NBATCH / 2, 512, 0, stream>>>(src, tgt, ws);
    reduce_mean<<<1, 256, 0, stream>>>(ws, (float*)d_out);
}

// Round 17
// 27.026 us; speedup vs baseline: 2.0204x; 1.8257x over previous
//
#include <hip/hip_runtime.h>
#include <hip/hip_bf16.h>

constexpr int NBATCH = 2048;   // B*T
constexpr int N      = 128;    // nodes
constexpr float INVTAU = 20.0f;   // 1/0.05
constexpr float EPSF   = 1e-8f;
constexpr float MUF    = 1.0f / 128.0f;   // mu = nu = 1/N
// K = expf(-20*sqrt(d2)) rounds to exactly 0.0f (even with denormal-
// preserving exp) iff 20*sqrt(d2) > 149*ln2 = 103.28, i.e. d2 > 26.66.
constexpr float D2_UNDERFLOW = 27.0f;

typedef __attribute__((ext_vector_type(8))) short short8;   // 8 x bf16 MFMA frag
typedef __attribute__((ext_vector_type(4))) float f32x4;    // MFMA accumulator
typedef __attribute__((ext_vector_type(2))) float f32x2;    // packed pair -> v_pk_fma_f32

static __device__ __forceinline__ float fastrcp(float x) {
    return __builtin_amdgcn_rcpf(x);    // v_rcp_f32, ~1e-7 rel err
}
static __device__ __forceinline__ float fastsqrt(float x) {
    return __builtin_amdgcn_sqrtf(x);   // raw v_sqrt_f32
}

// DPP cross-lane (VALU pipe, no DS op — r10: DS pipe was the bottleneck)
template <int CTRL>
static __device__ __forceinline__ float dpp_add(float s) {
    union { float f; int i; } a, b;
    a.f = s;
    b.i = __builtin_amdgcn_update_dpp(0, a.i, CTRL, 0xF, 0xF, false);
    return s + b.f;
}
template <int CTRL>
static __device__ __forceinline__ float dpp_min(float s) {
    union { float f; int i; } a, b;
    a.f = s;
    b.i = __builtin_amdgcn_update_dpp(0, a.i, CTRL, 0xF, 0xF, false);
    return fminf(s, b.f);
}
// all-reduce over a 16-lane row: row_ror 8,4,2,1
static __device__ __forceinline__ float row16_allreduce(float s) {
    s = dpp_add<0x128>(s);   // row_ror:8
    s = dpp_add<0x124>(s);   // row_ror:4
    s = dpp_add<0x122>(s);   // row_ror:2
    s = dpp_add<0x121>(s);   // row_ror:1
    return s;
}
static __device__ __forceinline__ float row16_minreduce(float s) {
    s = dpp_min<0x128>(s);
    s = dpp_min<0x124>(s);
    s = dpp_min<0x122>(s);
    s = dpp_min<0x121>(s);
    return s;
}
// all-reduce over an 8-lane group: quad_perm xor1, xor2, then half_mirror
static __device__ __forceinline__ float grp8_allreduce(float s) {
    s = dpp_add<0x0B1>(s);   // quad_perm [1,0,3,2]  (xor 1)
    s = dpp_add<0x04E>(s);   // quad_perm [2,3,0,1]  (xor 2)
    s = dpp_add<0x141>(s);   // row_half_mirror      (xor 7 within 8)
    return s;
}

// ROUND 17 = r11 (42.9us anchor) + exact-sparsity shortcut.
// After the MFMA produces d2 (kept in regs), a block-wide min-vote checks
// d2min > 27: then every K the slow path would compute is EXACTLY 0.0f,
// so u = mu/eps, v = nu/eps, loss = sum(u*K*C*v) = 0 exactly -> write 0,
// exit. The vote uses the SAME d2 registers the slow path would
// exponentiate, so fast<->slow equivalence is exact for ANY input and any
// MFMA rounding; branch is block-uniform and deterministic. Slow path is
// r11 verbatim. bounds(512,4) = the mapped no-spill point (r5/7/12/14/16
// all spilled above it). Tripwire: WRITE ~64 KB.
__global__ __launch_bounds__(512, 4)
void sinkhorn_batch(const float* __restrict__ srcg,
                    const float* __restrict__ tgtg,
                    float* __restrict__ lossg)
{
    // staging 32 KB; dead after phase 1 -> overlaid by sPart (128 cols x 36 f32)
    __shared__ ushort sStage[2 * N * 64];
    __shared__ float sX2[N], sY2[N];
    __shared__ float sVt[16 * 12];         // transposed v
    __shared__ float sRed[8];

    ushort* sA = sStage;
    ushort* sB = sStage + N * 64;
    float*  sPartF = reinterpret_cast<float*>(sStage);   // [col][36], 18 KB

    const int t  = threadIdx.x;
    const int l  = t & 63;
    const int w  = t >> 6;       // wave 0..7
    const int lx = l & 15;
    const int lh = l >> 4;       // 0..3
    const int bt = blockIdx.x;

    const float4* sg4 = reinterpret_cast<const float4*>(srcg + (size_t)bt * (N * 64));
    const float4* tg4 = reinterpret_cast<const float4*>(tgtg + (size_t)bt * (N * 64));

    // ---- phase 0: stage bf16 (swizzled, b128 stores) + norms via 8-lane DPP ----
    #pragma unroll
    for (int it = 0; it < 2; ++it) {
        int tp = t + 512 * it;         // 0..1023; 8 consecutive lanes = one row
        int r  = tp >> 3;
        int d8 = tp & 7;
        int f0 = tp * 2;
        float4 a0 = sg4[f0], a1 = sg4[f0 + 1];
        float4 b0 = tg4[f0], b1 = tg4[f0 + 1];
        float pa = a0.x * a0.x + a0.y * a0.y + a0.z * a0.z + a0.w * a0.w
                 + a1.x * a1.x + a1.y * a1.y + a1.z * a1.z + a1.w * a1.w;
        float pb = b0.x * b0.x + b0.y * b0.y + b0.z * b0.z + b0.w * b0.w
                 + b1.x * b1.x + b1.y * b1.y + b1.z * b1.z + b1.w * b1.w;
        pa = grp8_allreduce(pa);
        pb = grp8_allreduce(pb);
        if (d8 == 0) { sX2[r] = pa; sY2[r] = pb; }

        int idx = r * 64 + ((d8 ^ (r & 7)) << 3);   // b128 slot (16B aligned)
        union { __hip_bfloat162 h[4]; uint4 u; } ca, cb;
        ca.h[0] = __float22bfloat162_rn(make_float2(a0.x, a0.y));
        ca.h[1] = __float22bfloat162_rn(make_float2(a0.z, a0.w));
        ca.h[2] = __float22bfloat162_rn(make_float2(a1.x, a1.y));
        ca.h[3] = __float22bfloat162_rn(make_float2(a1.z, a1.w));
        cb.h[0] = __float22bfloat162_rn(make_float2(b0.x, b0.y));
        cb.h[1] = __float22bfloat162_rn(make_float2(b0.z, b0.w));
        cb.h[2] = __float22bfloat162_rn(make_float2(b1.x, b1.y));
        cb.h[3] = __float22bfloat162_rn(make_float2(b1.z, b1.w));
        *reinterpret_cast<uint4*>(&sA[idx]) = ca.u;
        *reinterpret_cast<uint4*>(&sB[idx]) = cb.u;
    }
    __syncthreads();

    // ---- phase 1: MFMA -> d2 (kept in regs), track thread-min ----
    float x2r[4], y2c[8];
    #pragma unroll
    for (int q = 0; q < 4; ++q) x2r[q] = sX2[16 * w + 4 * lh + q];
    #pragma unroll
    for (int tc = 0; tc < 8; ++tc) y2c[tc] = sY2[16 * tc + lx];

    short8 af0, af1;
    {
        int ra = 16 * w + lx;
        af0 = *reinterpret_cast<const short8*>(&sA[ra * 64 + (((0 + lh) ^ (ra & 7)) << 3)]);
        af1 = *reinterpret_cast<const short8*>(&sA[ra * 64 + (((4 + lh) ^ (ra & 7)) << 3)]);
    }

    f32x2 dd2[8][2];      // d2 pairs, same slots kk2 will occupy
    float dmin = 1e30f;
    #pragma unroll
    for (int tc = 0; tc < 8; ++tc) {
        int rb = 16 * tc + lx;
        short8 bf0 = *reinterpret_cast<const short8*>(&sB[rb * 64 + (((0 + lh) ^ (rb & 7)) << 3)]);
        short8 bf1 = *reinterpret_cast<const short8*>(&sB[rb * 64 + (((4 + lh) ^ (rb & 7)) << 3)]);
        f32x4 acc = (f32x4){0.f, 0.f, 0.f, 0.f};
        acc = __builtin_amdgcn_mfma_f32_16x16x32_bf16(af0, bf0, acc, 0, 0, 0);
        acc = __builtin_amdgcn_mfma_f32_16x16x32_bf16(af1, bf1, acc, 0, 0, 0);
        float d2[4];
        #pragma unroll
        for (int q = 0; q < 4; ++q) {
            d2[q] = fmaxf(x2r[q] + y2c[tc] - 2.0f * acc[q], 0.f);
            dmin = fminf(dmin, d2[q]);
        }
        dd2[tc][0] = (f32x2){d2[0], d2[1]};
        dd2[tc][1] = (f32x2){d2[2], d2[3]};
    }

    // block-wide min vote (wave: DPP row-min + 2 cross-row shuffles, one-time)
    dmin = row16_minreduce(dmin);
    dmin = fminf(dmin, __shfl_xor(dmin, 16));
    dmin = fminf(dmin, __shfl_xor(dmin, 32));
    if (l == 0) sRed[w] = dmin;
    if (t < N) sVt[(t & 15) * 12 + (t >> 4)] = 1.0f;   // v init (slow path)
    __syncthreads();   // also: staging reads done -> region becomes sPartF

    float gmin = fminf(fminf(fminf(sRed[0], sRed[1]), fminf(sRed[2], sRed[3])),
                       fminf(fminf(sRed[4], sRed[5]), fminf(sRed[6], sRed[7])));
    if (gmin > D2_UNDERFLOW) {
        // every K == 0.0f exactly -> pi == 0 -> frame loss == 0 exactly
        if (t == 0) lossg[bt] = 0.0f;
        return;
    }

    // ---- phase 2 (slow path): C,K from the register-resident d2 ----
    f32x2 kk2[8][2];      // kk2[tc][p] = {K[q=2p], K[q=2p+1]}
    unsigned ccp[8][2];   // packed bf16 C
    #pragma unroll
    for (int tc = 0; tc < 8; ++tc) {
        float cd[4];
        cd[0] = fastsqrt(dd2[tc][0].x);
        cd[1] = fastsqrt(dd2[tc][0].y);
        cd[2] = fastsqrt(dd2[tc][1].x);
        cd[3] = fastsqrt(dd2[tc][1].y);
        kk2[tc][0] = (f32x2){__expf(-INVTAU * cd[0]), __expf(-INVTAU * cd[1])};
        kk2[tc][1] = (f32x2){__expf(-INVTAU * cd[2]), __expf(-INVTAU * cd[3])};
        union { __hip_bfloat162 h; unsigned u; } p0, p1;
        p0.h = __float22bfloat162_rn(make_float2(cd[0], cd[1]));
        p1.h = __float22bfloat162_rn(make_float2(cd[2], cd[3]));
        ccp[tc][0] = p0.u;
        ccp[tc][1] = p1.u;
    }

    // ---- phase 3: Sinkhorn; u via DPP all-reduce, v via padded LDS partials ----
    f32x2 uu2[2];
    for (int iter = 0; iter < 5; ++iter) {
        // u_i = mu / (sum_j K[i][j] v[j] + eps): packed dots + DPP row-reduce
        f32x4 v03, v47;
        {
            const f32x4* pv = reinterpret_cast<const f32x4*>(&sVt[lx * 12]);
            v03 = pv[0];   // vv[0..3]  = v[16*0+lx .. 16*3+lx]
            v47 = pv[1];   // vv[4..7]
        }
        f32x2 p0 = (f32x2){0.f, 0.f}, p1 = (f32x2){0.f, 0.f};
        #pragma unroll
        for (int tc = 0; tc < 8; ++tc) {
            float vs = (tc < 4) ? v03[tc & 3] : v47[tc & 3];
            f32x2 vb = (f32x2){vs, vs};
            p0 = kk2[tc][0] * vb + p0;      // v_pk_fma_f32
            p1 = kk2[tc][1] * vb + p1;
        }
        float s0 = row16_allreduce(p0.x);
        float s1 = row16_allreduce(p0.y);
        float s2 = row16_allreduce(p1.x);
        float s3 = row16_allreduce(p1.y);
        uu2[0] = (f32x2){MUF * fastrcp(s0 + EPSF), MUF * fastrcp(s1 + EPSF)};
        uu2[1] = (f32x2){MUF * fastrcp(s2 + EPSF), MUF * fastrcp(s3 + EPSF)};
        // no barrier: u never touches LDS

        // v_j = nu / (sum_i K[i][j] u[i] + eps): per-lane 4-row partial ->
        // sPartF[col][w*4+lh] (stride 36: 2-way write aliasing = free),
        // then 128 threads cross-reduce with 8x b128 reads.
        #pragma unroll
        for (int tc = 0; tc < 8; ++tc) {
            f32x2 t2 = kk2[tc][0] * uu2[0] + kk2[tc][1] * uu2[1];
            sPartF[(tc * 16 + lx) * 36 + (w << 2) + lh] = t2.x + t2.y;
        }
        __syncthreads();
        if (t < N) {
            const f32x4* pr = reinterpret_cast<const f32x4*>(&sPartF[t * 36]);
            f32x4 a0 = pr[0], a1 = pr[1], a2 = pr[2], a3 = pr[3];
            f32x4 a4 = pr[4], a5 = pr[5], a6 = pr[6], a7 = pr[7];
            f32x4 ss = a0 + a1 + a2 + a3 + a4 + a5 + a6 + a7;
            float s = (ss[0] + ss[1]) + (ss[2] + ss[3]);
            sVt[(t & 15) * 12 + (t >> 4)] = MUF * fastrcp(s + EPSF);
        }
        __syncthreads();
    }

    // ---- phase 4: loss = sum u_i K_ij C_ij v_j (u, K, C register-resident) ----
    f32x4 v03, v47;
    {
        const f32x4* pv = reinterpret_cast<const f32x4*>(&sVt[lx * 12]);
        v03 = pv[0];
        v47 = pv[1];
    }

    float part = 0.f;
    #pragma unroll
    for (int tc = 0; tc < 8; ++tc) {
        union { unsigned u; float f; } e0, e1, e2, e3;
        e0.u = ccp[tc][0] << 16;
        e1.u = ccp[tc][0] & 0xFFFF0000u;
        e2.u = ccp[tc][1] << 16;
        e3.u = ccp[tc][1] & 0xFFFF0000u;
        f32x2 c0 = (f32x2){e0.f, e1.f};
        f32x2 c1 = (f32x2){e2.f, e3.f};
        f32x2 r2 = uu2[0] * kk2[tc][0] * c0 + uu2[1] * kk2[tc][1] * c1;
        float vs = (tc < 4) ? v03[tc & 3] : v47[tc & 3];
        part += (r2.x + r2.y) * vs;
    }

    // deterministic block reduce: DPP within 16, then 2 cross-row shuffles
    part = row16_allreduce(part);
    part += __shfl_xor(part, 16);
    part += __shfl_xor(part, 32);
    if (l == 0) sRed[w] = part;
    __syncthreads();
    if (t == 0) {
        float s = 0.f;
        #pragma unroll
        for (int i = 0; i < 8; ++i) s += sRed[i];
        lossg[bt] = s;
    }
}

// mean over 2048 per-frame losses -> d_out[0]
__global__ __launch_bounds__(256, 1)
void reduce_mean(const float* __restrict__ lossg, float* __restrict__ out)
{
    __shared__ float sRed[4];
    int t = threadIdx.x;
    float s = 0.f;
    #pragma unroll
    for (int it = 0; it < 8; ++it) s += lossg[t + 256 * it];
    #pragma unroll
    for (int off = 32; off >= 1; off >>= 1) s += __shfl_xor(s, off);
    if ((t & 63) == 0) sRed[t >> 6] = s;
    __syncthreads();
    if (t == 0) out[0] = (sRed[0] + sRed[1] + sRed[2] + sRed[3]) * (1.0f / 2048.0f);
}

extern "C" void kernel_launch(void* const* d_in, const int* in_sizes, int n_in,
                              void* d_out, int out_size, void* d_ws, size_t ws_size,
                              hipStream_t stream)
{
    const float* src = (const float*)d_in[0];
    const float* tgt = (const float*)d_in[1];
    float* ws = (float*)d_ws;                       // 2048 floats of scratch

    sinkhorn_batch<<<NBATCH, 512, 0, stream>>>(src, tgt, ws);
    reduce_mean<<<1, 256, 0, stream>>>(ws, (float*)d_out);
}